// Round 12
// baseline (118.727 us; speedup 1.0000x reference)
//
#include <hip/hip_runtime.h>
#include <hip/hip_bf16.h>

// LoRA-factored 3x3 conv. out fp32. Input dtypes runtime-detected.
// x: [16,128,56,56], A: [256,16], B: [16,1152] -> out: [16,256,56,56]
// R16 = R15 (~31.5us inferred, PASSED) restructured for residency/overlap:
// blocks split along px into 2 halves of 32 output px. 256 thr = 4 waves
// (2 px-tiles x 2 K-halves); LDS = 4 rows x 36-px window x 256B = 36.9KB
// -> 4 blocks/CU; grid 56x16=896 = 3.5x CUs -> dynamic balance (R15: 448
// blocks, 2/CU, single round, 64 CUs half-idle) + 4-deep cross-block phase
// overlap (stage||MFMA||epilogue). Staging = unified 2304-task loop
// (9x256 exact): 8 coalesced u16 loads -> one swizzled ds_write_b128;
// border zeroing via validity mask (no memsets).
// Verified carried (window-local): swizzled [p][c] layout slot^(p&7) pitch
// 256B, b128 read addressing, Bfrag hi/lo frag order (R11-15), C layout
// col=lane&15,row=(lane>>4)*4+reg, kh-reduce via LDS overlay, fp32 stage-2,
// detect (R3).

#define Bn 16
#define Cc 128
#define Hh 56
#define Ww 56
#define Ll (Hh * Ww)      // 3136
#define Rr 16
#define Oo 256
#define KF (Cc * 9)       // 1152
#define NKS 36            // K-steps: 1152/32
#define W36 36            // px-window slots per block
#define RPITCH 128        // u16 per pixel slot (=256B)
#define ROWBY (W36 * 256) // bytes per staged row: 9216
#define HB 2              // output rows per block

typedef __attribute__((ext_vector_type(8))) short bfrag_t;  // 8 bf16 (16B)
typedef __attribute__((ext_vector_type(4))) float f32x4;    // C frag

__device__ __forceinline__ float bf16_bits(unsigned short u) {
    return __uint_as_float(((unsigned)u) << 16);
}

__device__ __forceinline__ unsigned short bf16_rne(float f) {
    const unsigned u = __float_as_uint(f);
    const unsigned r = u + 0x7FFFu + ((u >> 16) & 1u);
    return (unsigned short)(r >> 16);
}

// bf16-packed detect (proven R3).
__device__ __forceinline__ bool detect_bf16(const void* __restrict__ p) {
    const unsigned* w = (const unsigned*)p;
    int c = 0;
#pragma unroll
    for (int i = 0; i < 32; ++i) {
        const unsigned e = (w[i] >> 7) & 0xFFu;
        c += (e >= 96u && e <= 144u) ? 1 : 0;
    }
    return c >= 20;
}

// ---- prep: Bfrag[kstep][hi/lo][lane][8e] bf16 (frag order, tap-major K),
//      Afp[o][r] fp32. (Unchanged from R11-R15 - harness-verified.)
__global__ __launch_bounds__(256) void prep_frag(
    const void* __restrict__ A, const void* __restrict__ Bm,
    unsigned short* __restrict__ Bfrag, float* __restrict__ Afp)
{
    const bool ab = detect_bf16(A);
    const bool bb = detect_bf16(Bm);
    const int i = blockIdx.x * 256 + threadIdx.x;
    if (i < NKS * 512) {
        const int kstep = i >> 9, rem = i & 511;
        const int l = rem >> 3, e = rem & 7;
        const int r = l & 15, g = l >> 4;
        const int kp = kstep * 32 + g * 8 + e;   // tap-major k'
        const int tap = kp >> 7, c = kp & 127;
        const int k = c * 9 + tap;               // torch Unfold order (c,kh,kw)
        const float v = bb ? bf16_bits(((const unsigned short*)Bm)[r * KF + k])
                           : ((const float*)Bm)[r * KF + k];
        const unsigned short hi = bf16_rne(v);
        const float lov = v - bf16_bits(hi);
        Bfrag[(kstep * 2 + 0) * 512 + rem] = hi;
        Bfrag[(kstep * 2 + 1) * 512 + rem] = bf16_rne(lov);
    }
    if (i < Oo * Rr) {
        Afp[i] = ab ? bf16_bits(((const unsigned short*)A)[i])
                    : ((const float*)A)[i];
    }
}

#define MFB(A, B, C) __builtin_amdgcn_mfma_f32_16x16x32_bf16((A), (B), (C), 0, 0, 0)

// ---- fused main: one block = (b, rows h0,h0+1, px-half). 4 waves =
//      2 px-tiles x 2 K-halves.
template<bool XB>
__device__ __forceinline__ void fused_body(
    const void* __restrict__ x,
    const unsigned short* __restrict__ Bfrag,
    const float* __restrict__ Afp,
    float* __restrict__ out,
    unsigned short* __restrict__ xs)      // 36864 B
{
    const int tid   = threadIdx.x;
    const int lane  = tid & 63;
    const int wv    = __builtin_amdgcn_readfirstlane(tid >> 6);  // wave 0..3
    const int t     = wv & 1;             // px-tile 0..1
    const int kh    = wv >> 1;            // K-half 0..1 (cb pair)
    const int hb    = blockIdx.x >> 1;
    const int half  = blockIdx.x & 1;     // px-half 0..1
    const int h0    = hb * HB;
    const int b     = blockIdx.y;
    const int wbase = half * 32;

    // ---- stage: 2304 tasks = 4 rows x 16 cslots x 36 window-px; 9 x 256.
    // Task: 8 coalesced u16 channel loads (one pixel) -> one swizzled
    // ds_write_b128 at byte rr*ROWBY + p*256 + ((cs^(p&7))<<4).
    // Borders (h or w out of range) write zeros via mask.
    {
#pragma unroll
        for (int it = 0; it < 9; ++it) {
            const int idx = it * 256 + tid;
            const int rr  = idx / 576;            // 576 = 16*36
            const int rem = idx - rr * 576;
            const int cs_ = rem / 36;
            const int p   = rem - cs_ * 36;
            const int hh  = h0 - 1 + rr;
            const int wi  = wbase + p - 1;
            const bool ok = (hh >= 0) & (hh < Hh) & (wi >= 0) & (wi < Ww);
            const int hhc = (hh < 0) ? 0 : (hh >= Hh ? Hh - 1 : hh);
            const int wic = (wi < 0) ? 0 : (wi >= Ww ? Ww - 1 : wi);
            const unsigned gb = (unsigned)(b * Cc * Ll + hhc * Ww + wic);
            const int c0 = cs_ * 8;
            bfrag_t v;
#pragma unroll
            for (int j = 0; j < 8; ++j) {
                if constexpr (XB) {
                    v[j] = (short)((const unsigned short*)x)[
                        gb + (unsigned)((c0 + j) * Ll)];
                } else {
                    v[j] = (short)bf16_rne(((const float*)x)[
                        gb + (unsigned)((c0 + j) * Ll)]);
                }
            }
            if (!ok) v = (bfrag_t){0, 0, 0, 0, 0, 0, 0, 0};
            const int sp = cs_ ^ (p & 7);
            *(bfrag_t*)((char*)xs + rr * ROWBY + p * 256 + sp * 16) = v;
        }
    }
    __syncthreads();

    // ---- stage 1: MFMA over this wave's K-half (cb in {2kh, 2kh+1}).
    const int col = lane & 15;
    const int g   = lane >> 4;
    const int px  = wbase + t * 16 + col;      // output pixel w (valid < 56)
    const int pxc = px < Ww ? px : Ww - 1;     // clamp (half 1 lanes 56..63)

    // 6 per-lane swizzled LDS byte offsets: [dw][cbi], window-local p2
    unsigned off6[6];
#pragma unroll
    for (int dwv = 0; dwv < 3; ++dwv)
#pragma unroll
        for (int cbi = 0; cbi < 2; ++cbi) {
            const int cb = kh * 2 + cbi;
            const int p2 = (pxc - wbase) + dwv;   // 0..35
            off6[dwv * 2 + cbi] = (unsigned)(p2 * 256 +
                (((cb * 4 + g) ^ (p2 & 7)) << 4));
        }

    f32x4 acc0 = {0.f, 0.f, 0.f, 0.f};
    f32x4 acc1 = {0.f, 0.f, 0.f, 0.f};
    const bfrag_t* __restrict__ bfp = (const bfrag_t*)Bfrag;

#pragma unroll
    for (int tap = 0; tap < 9; ++tap) {
        const int dh = tap / 3, dw = tap - dh * 3;
#pragma unroll
        for (int cbi = 0; cbi < 2; ++cbi) {
            const int cb = kh * 2 + cbi;
            const int ks = tap * 4 + cb;
            const bfrag_t ahi = bfp[(ks * 2 + 0) * 64 + lane];  // 16B/lane L2
            const bfrag_t alo = bfp[(ks * 2 + 1) * 64 + lane];
            const char* p0 = (const char*)xs + dh * ROWBY + off6[dw * 2 + cbi];
            const bfrag_t pf0 = *(const bfrag_t*)p0;            // 16B aligned
            const bfrag_t pf1 = *(const bfrag_t*)(p0 + ROWBY);
            acc0 = MFB(ahi, pf0, acc0);
            acc0 = MFB(alo, pf0, acc0);
            acc1 = MFB(ahi, pf1, acc1);
            acc1 = MFB(alo, pf1, acc1);
        }
    }

    // ---- LDS reuse: overlay partial-C on xs; reduce K-halves; stage 2.
    __syncthreads();
    float (*tmp2)[HB][Rr][34] = (float (*)[HB][Rr][34])xs;  // [2][2][16][34]

    // C layout: col=lane&15 (px), row=(lane>>4)*4+reg  [R11-R15 verified]
#pragma unroll
    for (int reg = 0; reg < 4; ++reg) {
        tmp2[kh][0][g * 4 + reg][t * 16 + col] = acc0[reg];
        tmp2[kh][1][g * 4 + reg][t * 16 + col] = acc1[reg];
    }
    __syncthreads();

    // epilogue lanes: pxe = lane&31 (32 px of this half), rowe = lane>>5
    const int pxe  = lane & 31;
    const int rowe = lane >> 5;
    float tv[Rr];
#pragma unroll
    for (int r = 0; r < Rr; ++r)
        tv[r] = tmp2[0][rowe][r][pxe] + tmp2[1][rowe][r][pxe];

    const int wout = wbase + pxe;
    const bool wok = (wout < Ww);
    const size_t obase = (size_t)b * Oo * Ll
                       + (size_t)((h0 + rowe) * Ww) + (size_t)wout;
#pragma unroll 4
    for (int j = 0; j < 64; ++j) {
        const int o = wv * 64 + j;                 // 4 waves x 64 = 256
        const float* Ao = Afp + (size_t)o * Rr;    // uniform -> s_load
        float s = 0.f;
#pragma unroll
        for (int r = 0; r < Rr; ++r) s += Ao[r] * tv[r];
        if (wok) out[obase + (size_t)o * Ll] = s;
    }
}

__global__ __launch_bounds__(256, 4) void fused_px(
    const void* __restrict__ x,
    const unsigned short* __restrict__ Bfrag,
    const float* __restrict__ Afp,
    float* __restrict__ out)
{
    __shared__ __align__(16) unsigned short xs[4 * W36 * RPITCH];   // 36864 B
    if (detect_bf16(x)) fused_body<true >(x, Bfrag, Afp, out, xs);
    else                fused_body<false>(x, Bfrag, Afp, out, xs);
}

// ---- fallback (ws too small): slow but correct, no workspace.
__global__ __launch_bounds__(256) void fused_fallback(
    const void* __restrict__ x, const void* __restrict__ A,
    const void* __restrict__ Bm, float* __restrict__ out)
{
    const bool xb = detect_bf16(x);
    const bool ab = detect_bf16(A);
    const bool bb = detect_bf16(Bm);
    const int gid = blockIdx.x * 256 + threadIdx.x;
    const int b = gid / Ll;
    const int l = gid - b * Ll;
    const int h = l / Ww, w = l - h * Ww;
    float acc[Rr];
#pragma unroll
    for (int r = 0; r < Rr; ++r) acc[r] = 0.f;
    const size_t xbase = (size_t)b * Cc * Ll;
    for (int c = 0; c < Cc; ++c) {
        const size_t xc = xbase + (size_t)c * Ll;
        float xv[9];
#pragma unroll
        for (int dh = 0; dh < 3; ++dh) {
            const int hh = h + dh - 1;
            const bool hok = (hh >= 0) & (hh < Hh);
#pragma unroll
            for (int dw = 0; dw < 3; ++dw) {
                const int ww = w + dw - 1;
                const bool ok = hok & (ww >= 0) & (ww < Ww);
                const size_t idx = xc + (size_t)(hh * Ww + ww);
                xv[dh*3+dw] = ok ? (xb ? bf16_bits(((const unsigned short*)x)[idx])
                                       : ((const float*)x)[idx]) : 0.f;
            }
        }
#pragma unroll
        for (int r = 0; r < Rr; ++r) {
            const size_t bo = (size_t)r * KF + (size_t)c * 9;
            float s = acc[r];
#pragma unroll
            for (int i = 0; i < 9; ++i)
                s += (bb ? bf16_bits(((const unsigned short*)Bm)[bo+i])
                         : ((const float*)Bm)[bo+i]) * xv[i];
            acc[r] = s;
        }
    }
    const size_t obase = (size_t)b * Oo * Ll + (size_t)l;
    for (int o = 0; o < Oo; ++o) {
        float s = 0.f;
#pragma unroll
        for (int r = 0; r < Rr; ++r)
            s += (ab ? bf16_bits(((const unsigned short*)A)[o*Rr+r])
                     : ((const float*)A)[o*Rr+r]) * acc[r];
        out[obase + (size_t)o * Ll] = s;
    }
}

extern "C" void kernel_launch(void* const* d_in, const int* in_sizes, int n_in,
                              void* d_out, int out_size, void* d_ws, size_t ws_size,
                              hipStream_t stream) {
    const void* x  = d_in[0];
    const void* A  = d_in[1];
    const void* Bm = d_in[2];
    for (int i = 0; i < n_in && i < 3; ++i) {
        const int s = in_sizes[i];
        if      (s == Bn * Cc * Ll) x  = d_in[i];
        else if (s == Oo * Rr)      A  = d_in[i];
        else if (s == Rr * KF)      Bm = d_in[i];
    }
    float* out = (float*)d_out;

    const size_t frag_bytes = (size_t)(NKS * 2 * 512) * 2;          // 73728
    const size_t afp_bytes  = (size_t)(Oo * Rr) * 4;                // 16384
    const size_t need       = frag_bytes + afp_bytes;               // 90112

    if (ws_size >= need) {
        unsigned short* Bfrag = (unsigned short*)d_ws;
        float* Afp = (float*)((char*)d_ws + frag_bytes);
        prep_frag<<<dim3(72), 256, 0, stream>>>(A, Bm, Bfrag, Afp);
        fused_px<<<dim3((Hh / HB) * 2, Bn), 256, 0, stream>>>(x, Bfrag, Afp, out);
    } else {
        fused_fallback<<<dim3((Bn * Ll) / 256), 256, 0, stream>>>(x, A, Bm, out);
    }
}

// Round 13
// 103.562 us; speedup vs baseline: 1.1464x; 1.1464x over previous
//
#include <hip/hip_runtime.h>
#include <hip/hip_bf16.h>

// LoRA-factored 3x3 conv. out fp32. Input dtypes runtime-detected.
// x: [16,128,56,56], A: [256,16], B: [16,1152] -> out: [16,256,56,56]
// R17 = R15 (best: total 103.5us, fused ~33us) + skip-lo:
//  - R16's px-split REGRESSED (52us, FETCH +80%: halves on different XCDs
//    re-fetch shared x lines; staging latency vs smaller compute). Reverted.
//  - absmax == 2^-7 on all-fp32-math rounds proves A/B arrive bf16-rounded
//    -> prep's lov = v - bf16(v) == 0 -> all `alo` MFMAs multiply by ZERO.
//    Detect (proven R3) and skip: halves Bfrag L2 latency chain (the
//    measured wall: 36 serialized ~250cy load->MFMA steps at VGPR=52,
//    MfmaUtil 3%) and halves MFMA count. fp32-B keeps full hi/lo path.
// Verified carried bytes (R15 PASSED): 512thr 8 waves = 4 px-tiles x 2
// K-halves, swizzled [px][c] LDS (slot^(px&7), pitch 256B), batched b128
// staging, b128 read addressing, Bfrag hi/lo frag order, C layout
// col=lane&15,row=(lane>>4)*4+reg, kh-reduce LDS overlay, fp32 stage-2.

#define Bn 16
#define Cc 128
#define Hh 56
#define Ww 56
#define Ll (Hh * Ww)      // 3136
#define Rr 16
#define Oo 256
#define KF (Cc * 9)       // 1152
#define NKS 36            // K-steps: 1152/32
#define W2 58             // padded px range
#define RPITCH 128        // u16 per pixel in LDS (=256B, no pad)
#define ROWB (W2 * RPITCH) // 7424 u16 per staged row
#define HB 2              // output rows per block

typedef __attribute__((ext_vector_type(8))) short bfrag_t;  // 8 bf16 (16B)
typedef __attribute__((ext_vector_type(4))) float f32x4;    // C frag

__device__ __forceinline__ float bf16_bits(unsigned short u) {
    return __uint_as_float(((unsigned)u) << 16);
}

__device__ __forceinline__ unsigned short bf16_rne(float f) {
    const unsigned u = __float_as_uint(f);
    const unsigned r = u + 0x7FFFu + ((u >> 16) & 1u);
    return (unsigned short)(r >> 16);
}

// bf16-packed detect (proven R3).
__device__ __forceinline__ bool detect_bf16(const void* __restrict__ p) {
    const unsigned* w = (const unsigned*)p;
    int c = 0;
#pragma unroll
    for (int i = 0; i < 32; ++i) {
        const unsigned e = (w[i] >> 7) & 0xFFu;
        c += (e >= 96u && e <= 144u) ? 1 : 0;
    }
    return c >= 20;
}

// ---- prep: Bfrag[kstep][hi/lo][lane][8e] bf16 (frag order, tap-major K),
//      Afp[o][r] fp32. (Unchanged from R11-R15 - harness-verified.)
__global__ __launch_bounds__(256) void prep_frag(
    const void* __restrict__ A, const void* __restrict__ Bm,
    unsigned short* __restrict__ Bfrag, float* __restrict__ Afp)
{
    const bool ab = detect_bf16(A);
    const bool bb = detect_bf16(Bm);
    const int i = blockIdx.x * 256 + threadIdx.x;
    if (i < NKS * 512) {
        const int kstep = i >> 9, rem = i & 511;
        const int l = rem >> 3, e = rem & 7;
        const int r = l & 15, g = l >> 4;
        const int kp = kstep * 32 + g * 8 + e;   // tap-major k'
        const int tap = kp >> 7, c = kp & 127;
        const int k = c * 9 + tap;               // torch Unfold order (c,kh,kw)
        const float v = bb ? bf16_bits(((const unsigned short*)Bm)[r * KF + k])
                           : ((const float*)Bm)[r * KF + k];
        const unsigned short hi = bf16_rne(v);
        const float lov = v - bf16_bits(hi);
        Bfrag[(kstep * 2 + 0) * 512 + rem] = hi;
        Bfrag[(kstep * 2 + 1) * 512 + rem] = bf16_rne(lov);
    }
    if (i < Oo * Rr) {
        Afp[i] = ab ? bf16_bits(((const unsigned short*)A)[i])
                    : ((const float*)A)[i];
    }
}

#define MFB(A, B, C) __builtin_amdgcn_mfma_f32_16x16x32_bf16((A), (B), (C), 0, 0, 0)

// ---- fused main: one block = (b, rows h0,h0+1). 8 waves = 4 px-tiles x 2 K-halves.
// BB = B-input-is-bf16: lo correction identically zero -> skip alo loads+MFMAs.
template<bool XB, bool BB>
__device__ __forceinline__ void fused_body(
    const void* __restrict__ x,
    const unsigned short* __restrict__ Bfrag,
    const float* __restrict__ Afp,
    float* __restrict__ out,
    unsigned short* __restrict__ xs)      // [4*ROWB] u16, 59392 B
{
    const int tid  = threadIdx.x;
    const int lane = tid & 63;
    const int wv   = __builtin_amdgcn_readfirstlane(tid >> 6);  // wave 0..7
    const int t    = wv & 3;              // px-tile 0..3
    const int kh   = wv >> 2;             // K-half 0..1 (cb pair)
    const int h0   = blockIdx.x * HB;
    const int b    = blockIdx.y;

    // ---- stage 4 x-rows (h0-1 .. h0+2) into swizzled LDS [px][c].
    // Per (row, cslot) task: lane l (w=l, px=l+1) loads 8 consecutive
    // channels (8 coalesced u16 row-loads) -> ONE ds_write_b128 at
    // byte = px*256 + ((cslot ^ (px&7))<<4). 64 tasks / 8 waves.
    {
        const int l   = lane;
        const bool lok = (l < Ww);
#pragma unroll
        for (int rr = 0; rr < HB + 2; ++rr) {
            const int hh = h0 - 1 + rr;
            unsigned short* xr = xs + rr * ROWB;
            if (hh >= 0 && hh < Hh) {
                if (lok) {
                    const unsigned gb = (unsigned)(b * Cc * Ll + hh * Ww + l);
#pragma unroll
                    for (int it = 0; it < 2; ++it) {
                        const int cs_ = it * 8 + wv;     // cslot 0..15
                        const int c0  = cs_ * 8;
                        bfrag_t v;
#pragma unroll
                        for (int j = 0; j < 8; ++j) {
                            if constexpr (XB) {
                                v[j] = (short)((const unsigned short*)x)[
                                    gb + (unsigned)((c0 + j) * Ll)];
                            } else {
                                v[j] = (short)bf16_rne(((const float*)x)[
                                    gb + (unsigned)((c0 + j) * Ll)]);
                            }
                        }
                        const int sp = cs_ ^ ((l + 1) & 7);
                        *(bfrag_t*)((char*)xr + (l + 1) * 256 + sp * 16) = v;
                    }
                }
            } else {
                // zero whole row: 3712 dwords, 512 threads
                unsigned* xw = (unsigned*)xr;
#pragma unroll
                for (int it = 0; it < 7; ++it) xw[it * 512 + tid] = 0u;
                if (tid < 3712 - 7 * 512) xw[7 * 512 + tid] = 0u;
            }
        }
        // zero px borders (px=0, px=57) on all rows (covers any swizzle)
        if (tid < 128) {
#pragma unroll
            for (int rr = 0; rr < HB + 2; ++rr) {
                xs[rr * ROWB + tid] = 0;
                xs[rr * ROWB + 57 * RPITCH + tid] = 0;
            }
        }
    }
    __syncthreads();

    // ---- stage 1: MFMA over this wave's K-half (cb in {2kh, 2kh+1}).
    const int col = lane & 15;
    const int g   = lane >> 4;
    const int px  = t * 16 + col;              // output pixel w (valid < 56)
    const int pxc = px < Ww ? px : Ww - 1;     // clamp lanes' px 56..63

    // 6 per-lane swizzled LDS byte offsets: [dw][cbi]
    unsigned off6[6];
#pragma unroll
    for (int dwv = 0; dwv < 3; ++dwv)
#pragma unroll
        for (int cbi = 0; cbi < 2; ++cbi) {
            const int cb = kh * 2 + cbi;
            const int p2 = pxc + dwv;          // window px-index w..w+2
            off6[dwv * 2 + cbi] = (unsigned)(p2 * 256 +
                (((cb * 4 + g) ^ (p2 & 7)) << 4));
        }

    f32x4 acc0 = {0.f, 0.f, 0.f, 0.f};
    f32x4 acc1 = {0.f, 0.f, 0.f, 0.f};
    const bfrag_t* __restrict__ bfp = (const bfrag_t*)Bfrag;

#pragma unroll
    for (int tap = 0; tap < 9; ++tap) {
        const int dh = tap / 3, dw = tap - dh * 3;
#pragma unroll
        for (int cbi = 0; cbi < 2; ++cbi) {
            const int cb = kh * 2 + cbi;
            const int ks = tap * 4 + cb;
            const bfrag_t ahi = bfp[(ks * 2 + 0) * 64 + lane];  // 16B/lane L2
            const char* p0 = (const char*)xs + dh * (ROWB * 2) + off6[dw * 2 + cbi];
            const bfrag_t pf0 = *(const bfrag_t*)p0;            // 16B aligned
            const bfrag_t pf1 = *(const bfrag_t*)(p0 + ROWB * 2);
            acc0 = MFB(ahi, pf0, acc0);
            acc1 = MFB(ahi, pf1, acc1);
            if constexpr (!BB) {
                // fp32 B: apply lo-correction fragments too
                const bfrag_t alo = bfp[(ks * 2 + 1) * 64 + lane];
                acc0 = MFB(alo, pf0, acc0);
                acc1 = MFB(alo, pf1, acc1);
            }
        }
    }

    // ---- LDS reuse: overlay partial-C on xs; reduce K-halves; stage 2.
    __syncthreads();
    float (*tmp2)[HB][Rr][66] = (float (*)[HB][Rr][66])xs;  // [2][2][16][66]

    // C layout: col=lane&15 (px), row=(lane>>4)*4+reg  [R11-R15 verified]
#pragma unroll
    for (int reg = 0; reg < 4; ++reg) {
        tmp2[kh][0][g * 4 + reg][t * 16 + col] = acc0[reg];
        tmp2[kh][1][g * 4 + reg][t * 16 + col] = acc1[reg];
    }
    __syncthreads();

    float tv0[Rr], tv1[Rr];
#pragma unroll
    for (int r = 0; r < Rr; ++r) {
        tv0[r] = tmp2[0][0][r][lane] + tmp2[1][0][r][lane];
        tv1[r] = tmp2[0][1][r][lane] + tmp2[1][1][r][lane];
    }

    const bool wok = (lane < Ww);
    const size_t obase = (size_t)b * Oo * Ll + (size_t)(h0 * Ww) + (size_t)lane;
#pragma unroll 4
    for (int j = 0; j < 32; ++j) {
        const int o = wv * 32 + j;                 // 8 waves x 32 = 256
        const float* Ao = Afp + (size_t)o * Rr;    // uniform -> s_load
        float s0 = 0.f, s1 = 0.f;
#pragma unroll
        for (int r = 0; r < Rr; ++r) {
            const float av = Ao[r];
            s0 += av * tv0[r];
            s1 += av * tv1[r];
        }
        if (wok) {
            out[obase + (size_t)o * Ll]      = s0;
            out[obase + (size_t)o * Ll + Ww] = s1;
        }
    }
}

__global__ __launch_bounds__(512, 4) void fused_ks(
    const void* __restrict__ x,
    const void* __restrict__ Bm,
    const unsigned short* __restrict__ Bfrag,
    const float* __restrict__ Afp,
    float* __restrict__ out)
{
    __shared__ __align__(16) unsigned short xs[4 * ROWB];   // 59392 B
    const bool xb = detect_bf16(x);
    const bool bb = detect_bf16(Bm);
    if (xb) { if (bb) fused_body<true , true >(x, Bfrag, Afp, out, xs);
              else    fused_body<true , false>(x, Bfrag, Afp, out, xs); }
    else    { if (bb) fused_body<false, true >(x, Bfrag, Afp, out, xs);
              else    fused_body<false, false>(x, Bfrag, Afp, out, xs); }
}

// ---- fallback (ws too small): slow but correct, no workspace.
__global__ __launch_bounds__(256) void fused_fallback(
    const void* __restrict__ x, const void* __restrict__ A,
    const void* __restrict__ Bm, float* __restrict__ out)
{
    const bool xb = detect_bf16(x);
    const bool ab = detect_bf16(A);
    const bool bb = detect_bf16(Bm);
    const int gid = blockIdx.x * 256 + threadIdx.x;
    const int b = gid / Ll;
    const int l = gid - b * Ll;
    const int h = l / Ww, w = l - h * Ww;
    float acc[Rr];
#pragma unroll
    for (int r = 0; r < Rr; ++r) acc[r] = 0.f;
    const size_t xbase = (size_t)b * Cc * Ll;
    for (int c = 0; c < Cc; ++c) {
        const size_t xc = xbase + (size_t)c * Ll;
        float xv[9];
#pragma unroll
        for (int dh = 0; dh < 3; ++dh) {
            const int hh = h + dh - 1;
            const bool hok = (hh >= 0) & (hh < Hh);
#pragma unroll
            for (int dw = 0; dw < 3; ++dw) {
                const int ww = w + dw - 1;
                const bool ok = hok & (ww >= 0) & (ww < Ww);
                const size_t idx = xc + (size_t)(hh * Ww + ww);
                xv[dh*3+dw] = ok ? (xb ? bf16_bits(((const unsigned short*)x)[idx])
                                       : ((const float*)x)[idx]) : 0.f;
            }
        }
#pragma unroll
        for (int r = 0; r < Rr; ++r) {
            const size_t bo = (size_t)r * KF + (size_t)c * 9;
            float s = acc[r];
#pragma unroll
            for (int i = 0; i < 9; ++i)
                s += (bb ? bf16_bits(((const unsigned short*)Bm)[bo+i])
                         : ((const float*)Bm)[bo+i]) * xv[i];
            acc[r] = s;
        }
    }
    const size_t obase = (size_t)b * Oo * Ll + (size_t)l;
    for (int o = 0; o < Oo; ++o) {
        float s = 0.f;
#pragma unroll
        for (int r = 0; r < Rr; ++r)
            s += (ab ? bf16_bits(((const unsigned short*)A)[o*Rr+r])
                     : ((const float*)A)[o*Rr+r]) * acc[r];
        out[obase + (size_t)o * Ll] = s;
    }
}

extern "C" void kernel_launch(void* const* d_in, const int* in_sizes, int n_in,
                              void* d_out, int out_size, void* d_ws, size_t ws_size,
                              hipStream_t stream) {
    const void* x  = d_in[0];
    const void* A  = d_in[1];
    const void* Bm = d_in[2];
    for (int i = 0; i < n_in && i < 3; ++i) {
        const int s = in_sizes[i];
        if      (s == Bn * Cc * Ll) x  = d_in[i];
        else if (s == Oo * Rr)      A  = d_in[i];
        else if (s == Rr * KF)      Bm = d_in[i];
    }
    float* out = (float*)d_out;

    const size_t frag_bytes = (size_t)(NKS * 2 * 512) * 2;          // 73728
    const size_t afp_bytes  = (size_t)(Oo * Rr) * 4;                // 16384
    const size_t need       = frag_bytes + afp_bytes;               // 90112

    if (ws_size >= need) {
        unsigned short* Bfrag = (unsigned short*)d_ws;
        float* Afp = (float*)((char*)d_ws + frag_bytes);
        prep_frag<<<dim3(72), 256, 0, stream>>>(A, Bm, Bfrag, Afp);
        fused_ks<<<dim3(Hh / HB, Bn), 512, 0, stream>>>(x, Bm, Bfrag, Afp, out);
    } else {
        fused_fallback<<<dim3((Bn * Ll) / 256), 256, 0, stream>>>(x, A, Bm, out);
    }
}